// Round 16
// baseline (155.860 us; speedup 1.0000x reference)
//
#include <hip/hip_runtime.h>
#include <hip/hip_bf16.h>
#include <math.h>

#define BS   8192
#define DD   768
#define NC   64
#define NCL  500
#define CS   100
#define NY   1000
#define EPSN 1e-12f

typedef __attribute__((ext_vector_type(8))) short bf16x8;
typedef __attribute__((ext_vector_type(4))) float f32x4;

union B8 { unsigned u[4]; bf16x8 v; uint4 q; };

__device__ inline unsigned short f2bf(float x) {
    __hip_bfloat16 h = __float2bfloat16(x);
    return *reinterpret_cast<unsigned short*>(&h);
}
__device__ inline unsigned pk2(float a, float b) {
    return (unsigned)f2bf(a) | ((unsigned)f2bf(b) << 16);
}

#define FMA4(acc, s, v) { (acc).x = fmaf((s), (v).x, (acc).x); \
                          (acc).y = fmaf((s), (v).y, (acc).y); \
                          (acc).z = fmaf((s), (v).z, (acc).z); \
                          (acc).w = fmaf((s), (v).w, (acc).w); }

#define MFMA_(a, b, c) __builtin_amdgcn_mfma_f32_16x16x32_bf16((a).v, (b).v, (c), 0, 0, 0)

// ===== K1: score MFMA deep-pipe (400) || tmat MFMA deep-pipe (128) ||
//           gram ksplit (256) || U (32) =====
// R15 fix: k_front was ISSUE-DEPTH-bound (~2.5 loads in flight -> 2.1 TB/s;
// grid size 616 vs 944 changed nothing). New: pack C-granules ONCE per k-range
// (one barrier), then barrier-free steady loop with 2-deep named-register
// prefetch -> 8-16 loads outstanding per wave.
__global__ __launch_bounds__(256) void k_front(
    const float* __restrict__ clusters, const float* __restrict__ C,
    const float* __restrict__ W, const float* __restrict__ X,
    float* __restrict__ gramP, float* __restrict__ Up,
    float* __restrict__ SP, unsigned short* __restrict__ Tb) {
    __shared__ __align__(16) char smem_raw[49152];
    int b = blockIdx.x, tid = threadIdx.x;
    if (b < 400) {
        // score partial: rows rt*64..+63, samples sp*4..+3, k-half ks*384.
        int rt = b / 50, q2 = b % 50, sp = q2 >> 1, ks = q2 & 1;
        int kb = ks * 384;
        uint4 (*CbL)[64] = (uint4(*)[64])smem_raw;   // [48][64] granules, 48 KB
        int r0 = rt * 64;
        int w  = tid >> 6, l = tid & 63;
        int l15 = l & 15;
        int rowA = r0 + w*16 + l15;
        int rcl  = rowA < NCL ? rowA : (NCL - 1);    // clamp; rows >=500 unread
        int kq   = l >> 4;
        const float* ab = clusters + (size_t)rcl * CS * DD + (size_t)sp * 4 * DD
                        + kb + kq * 8;
        // ---- pack 48 granules for [kb, kb+384) : ONE barrier ----
        #pragma unroll
        for (int u = 0; u < 12; ++u) {
            int gi = (tid >> 6) + u * 4;
            int n  = tid & 63;
            const float* cp = C + (size_t)(kb + gi*8) * 64 + n;
            uint4 gr;
            gr.x = pk2(cp[0],   cp[64]);
            gr.y = pk2(cp[128], cp[192]);
            gr.z = pk2(cp[256], cp[320]);
            gr.w = pk2(cp[384], cp[448]);
            CbL[gi][n] = gr;
        }
        __syncthreads();
        f32x4 acc[4];
        #pragma unroll
        for (int ng = 0; ng < 4; ++ng) acc[ng] = (f32x4){0.f, 0.f, 0.f, 0.f};
        float4 A0[8], A1[8];
        // LOADA: 4 samples x 32B for chunk c (8 independent float4 loads)
        #define LOADA(dst, c) { \
            dst[0] = *(const float4*)(ab + (c)*32); \
            dst[1] = *(const float4*)(ab + (c)*32 + 4); \
            dst[2] = *(const float4*)(ab + DD + (c)*32); \
            dst[3] = *(const float4*)(ab + DD + (c)*32 + 4); \
            dst[4] = *(const float4*)(ab + 2*DD + (c)*32); \
            dst[5] = *(const float4*)(ab + 2*DD + (c)*32 + 4); \
            dst[6] = *(const float4*)(ab + 3*DD + (c)*32); \
            dst[7] = *(const float4*)(ab + 3*DD + (c)*32 + 4); }
        #define COMPS(src, c) { \
            B8 b0, b1, b2, b3; \
            b0.q = CbL[(c)*4 + kq][l15];      b1.q = CbL[(c)*4 + kq][l15 + 16]; \
            b2.q = CbL[(c)*4 + kq][l15 + 32]; b3.q = CbL[(c)*4 + kq][l15 + 48]; \
            _Pragma("unroll") \
            for (int ss = 0; ss < 4; ++ss) { \
                B8 a; \
                a.u[0] = pk2(src[ss*2].x,   src[ss*2].y); \
                a.u[1] = pk2(src[ss*2].z,   src[ss*2].w); \
                a.u[2] = pk2(src[ss*2+1].x, src[ss*2+1].y); \
                a.u[3] = pk2(src[ss*2+1].z, src[ss*2+1].w); \
                acc[0] = MFMA_(a, b0, acc[0]); acc[1] = MFMA_(a, b1, acc[1]); \
                acc[2] = MFMA_(a, b2, acc[2]); acc[3] = MFMA_(a, b3, acc[3]); } }
        LOADA(A0, 0);
        #pragma unroll
        for (int c = 0; c < 12; c += 2) {
            LOADA(A1, c + 1);
            COMPS(A0, c);
            if (c + 2 < 12) LOADA(A0, c + 2);
            COMPS(A1, c + 1);
        }
        #undef LOADA
        #undef COMPS
        int rw = r0 + w*16 + kq * 4;                  // D layout (m89)
        float* SPs = SP + (size_t)(sp * 2 + ks) * 32768;
        #pragma unroll
        for (int ng = 0; ng < 4; ++ng) {
            int n = ng*16 + l15;
            #pragma unroll
            for (int r = 0; r < 4; ++r)
                SPs[(size_t)(rw + r) * 64 + n] = acc[ng][r];
        }
    } else if (b < 528) {
        // T = X @ C via MFMA, full k, two pack phases (3 barriers), bf16 out.
        uint4 (*CbL)[64] = (uint4(*)[64])smem_raw;   // [48][64]
        int r0 = (b - 400) * 64;
        int w  = tid >> 6, l = tid & 63;
        int l15 = l & 15;
        int rowA = r0 + w*16 + l15;
        int kq   = l >> 4;
        f32x4 acc[4];
        #pragma unroll
        for (int ng = 0; ng < 4; ++ng) acc[ng] = (f32x4){0.f, 0.f, 0.f, 0.f};
        #pragma unroll
        for (int half = 0; half < 2; ++half) {
            int kb = half * 384;
            if (half) __syncthreads();               // all reads of CbL done
            #pragma unroll
            for (int u = 0; u < 12; ++u) {
                int gi = (tid >> 6) + u * 4;
                int n  = tid & 63;
                const float* cp = C + (size_t)(kb + gi*8) * 64 + n;
                uint4 gr;
                gr.x = pk2(cp[0],   cp[64]);
                gr.y = pk2(cp[128], cp[192]);
                gr.z = pk2(cp[256], cp[320]);
                gr.w = pk2(cp[384], cp[448]);
                CbL[gi][n] = gr;
            }
            __syncthreads();
            const float* xh = X + (size_t)rowA * DD + kb + kq * 8;
            float4 A0[4], A1[4];
            // LOADX: 2 chunks (64 k) = 4 independent float4 loads
            #define LOADX(dst, c) { \
                dst[0] = *(const float4*)(xh + (c)*32); \
                dst[1] = *(const float4*)(xh + (c)*32 + 4); \
                dst[2] = *(const float4*)(xh + (c)*32 + 32); \
                dst[3] = *(const float4*)(xh + (c)*32 + 36); }
            #define COMPX(src, c) { \
                _Pragma("unroll") \
                for (int cc = 0; cc < 2; ++cc) { \
                    B8 b0, b1, b2, b3, a; \
                    b0.q = CbL[((c)+cc)*4 + kq][l15]; \
                    b1.q = CbL[((c)+cc)*4 + kq][l15 + 16]; \
                    b2.q = CbL[((c)+cc)*4 + kq][l15 + 32]; \
                    b3.q = CbL[((c)+cc)*4 + kq][l15 + 48]; \
                    a.u[0] = pk2(src[cc*2].x,   src[cc*2].y); \
                    a.u[1] = pk2(src[cc*2].z,   src[cc*2].w); \
                    a.u[2] = pk2(src[cc*2+1].x, src[cc*2+1].y); \
                    a.u[3] = pk2(src[cc*2+1].z, src[cc*2+1].w); \
                    acc[0] = MFMA_(a, b0, acc[0]); acc[1] = MFMA_(a, b1, acc[1]); \
                    acc[2] = MFMA_(a, b2, acc[2]); acc[3] = MFMA_(a, b3, acc[3]); } }
            LOADX(A0, 0);
            #pragma unroll
            for (int s = 0; s < 6; s += 2) {
                LOADX(A1, (s + 1) * 2);
                COMPX(A0, s * 2);
                if (s + 2 < 6) LOADX(A0, (s + 2) * 2);
                COMPX(A1, (s + 1) * 2);
            }
            #undef LOADX
            #undef COMPX
        }
        int rw = r0 + w*16 + kq * 4;
        #pragma unroll
        for (int ng = 0; ng < 4; ++ng) {
            int n = ng*16 + l15;
            #pragma unroll
            for (int r = 0; r < 4; ++r)
                Tb[(size_t)(rw + r) * 64 + n] = f2bf(acc[ng][r]);
        }
    } else if (b < 784) {
        // gram k-split partials (verified R11 body)
        int q  = b - 528;
        int j  = q & 63, ks = q >> 6;
        int i   = tid & 63;
        int seg = tid >> 6;
        int k0  = ks * 192 + seg * 48;
        float p = 0.f;
        for (int k = k0; k < k0 + 48; ++k)
            p += C[k * NC + i] * C[k * NC + j];
        float (*red)[64] = (float(*)[64])smem_raw;
        red[seg][i] = p;
        __syncthreads();
        if (seg == 0)
            gramP[(size_t)ks * 4096 + i * NC + j] =
                red[0][i] + red[1][i] + red[2][i] + red[3][i];
    } else {
        // U-partial = C^T[kslice] @ W[kslice][128 cols] (verified f32 body)
        int q  = b - 784;
        int nt = q >> 2, ks = q & 3;
        int n0 = nt * 128, kb = ks * 192;
        float (*Cu)[68]  = (float(*)[68])smem_raw;               // [32][68]
        float (*Wu)[132] = (float(*)[132])(smem_raw + 8704);     // [32][132]
        int tx = tid & 15, ty = tid >> 4;
        float4 a0[4], a1[4];
        #pragma unroll
        for (int i = 0; i < 4; ++i) { a0[i] = make_float4(0,0,0,0); a1[i] = make_float4(0,0,0,0); }
        for (int kc = kb; kc < kb + 192; kc += 32) {
            __syncthreads();
            {   int i4 = tid & 15, kk = tid >> 4;
                *((float4*)&Cu[kk][i4*4])    = *((const float4*)(C + (size_t)(kc+kk)*64 + i4*4));
                *((float4*)&Cu[kk+16][i4*4]) = *((const float4*)(C + (size_t)(kc+kk+16)*64 + i4*4));
            }
            {   int nf = tid & 31, kq2 = tid >> 5;
                #pragma unroll
                for (int u = 0; u < 4; ++u) {
                    int k = kq2 + u * 8;
                    int n = n0 + nf * 4;
                    float4 v = {0.f, 0.f, 0.f, 0.f};
                    if (n < NY) v = *((const float4*)(W + (size_t)(kc + k) * NY + n));
                    *((float4*)&Wu[k][nf*4]) = v;
                }
            }
            __syncthreads();
            #pragma unroll 8
            for (int k = 0; k < 32; ++k) {
                float4 ci = *((float4*)&Cu[k][ty*4]);
                float4 w0 = *((float4*)&Wu[k][tx*8]);
                float4 w1 = *((float4*)&Wu[k][tx*8+4]);
                FMA4(a0[0], ci.x, w0); FMA4(a1[0], ci.x, w1);
                FMA4(a0[1], ci.y, w0); FMA4(a1[1], ci.y, w1);
                FMA4(a0[2], ci.z, w0); FMA4(a1[2], ci.z, w1);
                FMA4(a0[3], ci.w, w0); FMA4(a1[3], ci.w, w1);
            }
        }
        float* Ups = Up + (size_t)ks * 64000;
        #pragma unroll
        for (int i = 0; i < 4; ++i) {
            int irow = ty * 4 + i;
            int n = n0 + tx * 8;
            if (n < NY)     *((float4*)(Ups + (size_t)irow * NY + n))     = a0[i];
            if (n + 4 < NY) *((float4*)(Ups + (size_t)irow * NY + n + 4)) = a1[i];
        }
    }
}

// ===== K2: inv (block 0) || S-reduce 50->1 + abs (blocks 1..16) — R14 verified =====
__global__ __launch_bounds__(256) void k_mid(
    const float* __restrict__ gramP, const float* __restrict__ SP,
    float* __restrict__ ginv, float* __restrict__ Sfin) {
    int blk = blockIdx.x, tid = threadIdx.x;
    if (blk == 0) {
        int c = tid & 63;
        int q = tid >> 6;
        float a[16], bb[16];
        #pragma unroll
        for (int i = 0; i < 16; ++i) {
            int r = q * 16 + i;
            size_t off = (size_t)r * 64 + c;
            a[i]  = gramP[off] + gramP[4096 + off] + gramP[8192 + off] + gramP[12288 + off];
            bb[i] = (r == c) ? 1.f : 0.f;
        }
        __shared__ float asr[2][64];
        __shared__ float bsr[2][64];
        for (int p = 0; p < 64; ++p) {
            int qp  = p >> 4;
            int lp  = p & 15;
            int par = p & 1;
            if (q == qp) {
                float ap = 0.f, bp = 0.f;
                #pragma unroll
                for (int i = 0; i < 16; ++i)
                    if (i == lp) { ap = a[i]; bp = bb[i]; }
                float App = __shfl(ap, p);
                float s   = 1.0f / App;
                asr[par][c] = ap * s;
                bsr[par][c] = bp * s;
            }
            __syncthreads();
            float as_ = asr[par][c];
            float bs_ = bsr[par][c];
            #pragma unroll
            for (int i = 0; i < 16; ++i) {
                float f = __shfl(a[i], p);
                bool isp = (q == qp) && (i == lp);
                a[i]  = isp ? as_ : fmaf(-f, as_, a[i]);
                bb[i] = isp ? bs_ : fmaf(-f, bs_, bb[i]);
            }
        }
        #pragma unroll
        for (int i = 0; i < 16; ++i)
            ginv[(q * 16 + i) * 64 + c] = bb[i];
    } else {
        int e = blk - 1;                              // 0..15
        for (int t = tid; t < 500; t += 256) {
            size_t off = (size_t)e * 2000 + (size_t)t * 4;
            float4 s0 = {0.f,0.f,0.f,0.f}, s1 = {0.f,0.f,0.f,0.f};
            #pragma unroll
            for (int p = 0; p < 50; p += 2) {
                float4 v0 = *((const float4*)(SP + (size_t)p * 32768 + off));
                float4 v1 = *((const float4*)(SP + (size_t)(p+1) * 32768 + off));
                s0.x += v0.x; s0.y += v0.y; s0.z += v0.z; s0.w += v0.w;
                s1.x += v1.x; s1.y += v1.y; s1.z += v1.z; s1.w += v1.w;
            }
            float4 o = {fabsf(s0.x + s1.x), fabsf(s0.y + s1.y),
                        fabsf(s0.z + s1.z), fabsf(s0.w + s1.w)};
            *((float4*)(Sfin + off)) = o;
        }
    }
}

// ====== K3: Vb = bf16[(Ginv @ sum Up)^T] (0..15) || sparse (16) — R14 verified ======
__global__ __launch_bounds__(256) void k_vc(
    const float* __restrict__ ginv, const float* __restrict__ Up,
    const float* __restrict__ Sfin, unsigned short* __restrict__ Vb,
    float* __restrict__ out2) {
    __shared__ __align__(16) char smem_raw[34816];
    int blk = blockIdx.x, tid = threadIdx.x;
    if (blk == 16) {
        __shared__ float colred[4][64];
        __shared__ float rn[64];
        __shared__ float trc[64];
        __shared__ float r1[4], r2[4];
        int c = tid & 63, seg = tid >> 6;
        float p = 0.f;
        for (int r = seg; r < NCL; r += 4) {
            float s = Sfin[r * 64 + c];
            p += s * s;
        }
        colred[seg][c] = p;
        __syncthreads();
        if (seg == 0) {
            float n2  = colred[0][c] + colred[1][c] + colred[2][c] + colred[3][c];
            float inv = 1.0f / fmaxf(sqrtf(n2), EPSN);
            rn[c]  = inv;
            trc[c] = n2 * inv * inv;
        }
        __syncthreads();
        float l1p = 0.f, l2p = 0.f;
        for (int r = tid; r < NCL; r += 256) {
            float rs = 0.f;
            #pragma unroll
            for (int cc = 0; cc < 64; ++cc)
                rs += Sfin[r * 64 + cc] * rn[cc];
            l1p += rs;
            l2p += rs * rs;
        }
        #pragma unroll
        for (int off = 32; off > 0; off >>= 1) {
            l1p += __shfl_down(l1p, off);
            l2p += __shfl_down(l2p, off);
        }
        int wave = tid >> 6, lane = tid & 63;
        if (lane == 0) { r1[wave] = l1p; r2[wave] = l2p; }
        __syncthreads();
        if (tid == 0) {
            float L1 = r1[0] + r1[1] + r1[2] + r1[3];
            float L2 = r2[0] + r2[1] + r2[2] + r2[3];
            float tr = 0.f;
            #pragma unroll
            for (int cc = 0; cc < 64; ++cc) tr += trc[cc];
            out2[0] = L1;
            out2[1] = L2 - tr;
        }
        return;
    }
    float (*Us)[68] = (float(*)[68])smem_raw;                     // [64][68]
    float (*Gs)[68] = (float(*)[68])(smem_raw + 64*68*4);         // [64][68]
    int c0 = blk * 64;
    int tx = tid & 15, ty = tid >> 4;
    const float* Up0 = Up;
    const float* Up1 = Up + 64000;
    const float* Up2 = Up + 128000;
    const float* Up3 = Up + 192000;
    #pragma unroll
    for (int p = 0; p < 4; ++p) {
        int f = tid + p * 256;
        int j = f >> 4, n4 = f & 15;
        int n = c0 + n4 * 4;
        float4 v = {0.f, 0.f, 0.f, 0.f};
        if (n < NY) {
            float4 u0 = *((const float4*)(Up0 + (size_t)j * NY + n));
            float4 u1 = *((const float4*)(Up1 + (size_t)j * NY + n));
            float4 u2 = *((const float4*)(Up2 + (size_t)j * NY + n));
            float4 u3 = *((const float4*)(Up3 + (size_t)j * NY + n));
            v.x = u0.x + u1.x + u2.x + u3.x;
            v.y = u0.y + u1.y + u2.y + u3.y;
            v.z = u0.z + u1.z + u2.z + u3.z;
            v.w = u0.w + u1.w + u2.w + u3.w;
        }
        *((float4*)&Us[j][n4*4]) = v;
        *((float4*)&Gs[j][n4*4]) = *((const float4*)(ginv + (size_t)j * 64 + n4*4));
    }
    __syncthreads();
    float4 acc[4];
    #pragma unroll
    for (int i = 0; i < 4; ++i) acc[i] = make_float4(0.f,0.f,0.f,0.f);
    for (int j0 = 0; j0 < 64; j0 += 4) {
        #pragma unroll
        for (int jj = 0; jj < 4; ++jj) {
            float4 g = *((float4*)&Gs[j0+jj][ty*4]);   // Ginv symmetric
            float4 u = *((float4*)&Us[j0+jj][tx*4]);
            FMA4(acc[0], g.x, u);
            FMA4(acc[1], g.y, u);
            FMA4(acc[2], g.z, u);
            FMA4(acc[3], g.w, u);
        }
    }
    #pragma unroll
    for (int i = 0; i < 4; ++i) {
        int krow = ty * 4 + i;
        Vb[(size_t)(c0 + tx*4 + 0) * 64 + krow] = f2bf(acc[i].x);
        Vb[(size_t)(c0 + tx*4 + 1) * 64 + krow] = f2bf(acc[i].y);
        Vb[(size_t)(c0 + tx*4 + 2) * 64 + krow] = f2bf(acc[i].z);
        Vb[(size_t)(c0 + tx*4 + 3) * 64 + krow] = f2bf(acc[i].w);
    }
}

// ===== K4: y = T @ V + b via MFMA, 128x128, zero LDS — R14 verified =====
__global__ __launch_bounds__(256) void k_ypred(
    const uint4* __restrict__ Tbq, const uint4* __restrict__ Vbq,
    const float* __restrict__ bh, float* __restrict__ Y) {
    int blk = blockIdx.x, tid = threadIdx.x;
    int rb = blk >> 3, cb = blk & 7;
    int r0g = rb * 128, c0g = cb * 128;
    int w = tid >> 6, l = tid & 63;
    int wr = (w >> 1) * 64, wc = (w & 1) * 64;
    int kq = l >> 4, ln = l & 15;
    f32x4 acc[4][4];
    #pragma unroll
    for (int rg = 0; rg < 4; ++rg)
        #pragma unroll
        for (int ng = 0; ng < 4; ++ng) acc[rg][ng] = (f32x4){0.f,0.f,0.f,0.f};
    #pragma unroll
    for (int ks = 0; ks < 2; ++ks) {
        B8 a[4], bb[4];
        #pragma unroll
        for (int rg = 0; rg < 4; ++rg) {
            int row = r0g + wr + rg*16 + ln;
            a[rg].q = Tbq[(size_t)row * 8 + ks*4 + kq];
        }
        #pragma unroll
        for (int ng = 0; ng < 4; ++ng) {
            int n = c0g + wc + ng*16 + ln;
            bb[ng].q = Vbq[(size_t)n * 8 + ks*4 + kq];
        }
        #pragma unroll
        for (int rg = 0; rg < 4; ++rg)
            #pragma unroll
            for (int ng = 0; ng < 4; ++ng)
                acc[rg][ng] = __builtin_amdgcn_mfma_f32_16x16x32_bf16(
                    a[rg].v, bb[ng].v, acc[rg][ng], 0, 0, 0);
    }
    #pragma unroll
    for (int ng = 0; ng < 4; ++ng) {
        int n = c0g + wc + ng*16 + ln;
        if (n < NY) {
            float bias = bh[n];
            #pragma unroll
            for (int rg = 0; rg < 4; ++rg) {
                int row = r0g + wr + rg*16 + kq*4;
                #pragma unroll
                for (int r = 0; r < 4; ++r)
                    Y[(size_t)(row + r) * NY + n] = acc[rg][ng][r] + bias;
            }
        }
    }
}

extern "C" void kernel_launch(void* const* d_in, const int* in_sizes, int n_in,
                              void* d_out, int out_size, void* d_ws, size_t ws_size,
                              hipStream_t stream) {
    const float* X        = (const float*)d_in[0];   // [8192,768]
    const float* clusters = (const float*)d_in[1];   // [500,100,768]
    const float* C        = (const float*)d_in[2];   // [768,64]
    const float* W        = (const float*)d_in[3];   // [768,1000]
    const float* bh       = (const float*)d_in[4];   // [1000]
    float* out = (float*)d_out;                      // y_pred, L1, L2
    float* ws  = (float*)d_ws;

    float* gramP = ws;                    // 4 x 4096 = 16384
    float* ginv  = gramP + 16384;         // 4096
    float* Up    = ginv  + 4096;          // 4 x 64000 = 256000
    float* SP    = Up    + 256000;        // 50 x 32768 = 1,638,400
    float* Sfin  = SP    + 1638400;       // 32768 (500x64 used)
    float* TbF   = Sfin  + 32768;         // 262144 floats (Tb bf16, 1 MB)
    float* VbF   = TbF   + 262144;        // 32768 floats (Vb bf16, 128 KB)

    unsigned short* Tb = (unsigned short*)TbF;
    unsigned short* Vb = (unsigned short*)VbF;

    k_front <<<dim3(816), dim3(256), 0, stream>>>(clusters, C, W, X, gramP, Up, SP, Tb);
    k_mid   <<<dim3(17),  dim3(256), 0, stream>>>(gramP, SP, ginv, Sfin);
    k_vc    <<<dim3(17),  dim3(256), 0, stream>>>(ginv, Up, Sfin, Vb, out + (size_t)BS * NY);
    k_ypred <<<dim3(512), dim3(256), 0, stream>>>((const uint4*)Tb, (const uint4*)Vb, bh, out);
}

// Round 17
// 149.193 us; speedup vs baseline: 1.0447x; 1.0447x over previous
//
#include <hip/hip_runtime.h>
#include <hip/hip_bf16.h>
#include <math.h>

#define BS   8192
#define DD   768
#define NC   64
#define NCL  500
#define CS   100
#define NY   1000
#define EPSN 1e-12f

typedef __attribute__((ext_vector_type(8))) short bf16x8;
typedef __attribute__((ext_vector_type(4))) float f32x4;

union B8 { unsigned u[4]; bf16x8 v; uint4 q; };

__device__ inline unsigned short f2bf(float x) {
    __hip_bfloat16 h = __float2bfloat16(x);
    return *reinterpret_cast<unsigned short*>(&h);
}
__device__ inline unsigned pk2(float a, float b) {
    return (unsigned)f2bf(a) | ((unsigned)f2bf(b) << 16);
}

#define FMA4(acc, s, v) { (acc).x = fmaf((s), (v).x, (acc).x); \
                          (acc).y = fmaf((s), (v).y, (acc).y); \
                          (acc).z = fmaf((s), (v).z, (acc).z); \
                          (acc).w = fmaf((s), (v).w, (acc).w); }

// ===== K1: score MFMA (200) || tmat MFMA (128) || gram ksplit (256) || U (32) =====
// Verified R13 bodies (best measured config: 146.6us total, k_front ~87us).
__global__ __launch_bounds__(256) void k_front(
    const float* __restrict__ clusters, const float* __restrict__ C,
    const float* __restrict__ W, const float* __restrict__ X,
    float* __restrict__ gramP, float* __restrict__ Up,
    float* __restrict__ SP, unsigned short* __restrict__ Tb) {
    __shared__ __align__(16) char smem_raw[25600];
    int b = blockIdx.x, tid = threadIdx.x;
    if (b < 200) {
        // score partial: rows rt*64..+63, samples sp*4..+3 (K-eff = 4*768)
        int rt = b / 25, sp = b % 25;
        uint4 (*CbL)[64] = (uint4(*)[64])smem_raw;    // [8][64] C granules, 8 KB
        int r0 = rt * 64;
        int w  = tid >> 6, l = tid & 63;
        int rowA = r0 + w*16 + (l & 15);
        int rcl  = rowA < NCL ? rowA : (NCL - 1);     // clamp; rows >=500 unread
        int kq   = l >> 4;
        const float* ab = clusters + (size_t)rcl * CS * DD + (size_t)sp * 4 * DD + kq * 8;
        f32x4 acc[4];
        #pragma unroll
        for (int ng = 0; ng < 4; ++ng) acc[ng] = (f32x4){0.f, 0.f, 0.f, 0.f};
        for (int kc = 0; kc < DD; kc += 64) {
            __syncthreads();
            #pragma unroll
            for (int u = 0; u < 2; ++u) {             // pack C[kc..kc+64) granules
                int g = (tid >> 6) + u*4;
                int n = tid & 63;
                const float* cp = C + (size_t)(kc + g*8) * 64 + n;
                uint4 gr;
                gr.x = pk2(cp[0],   cp[64]);
                gr.y = pk2(cp[128], cp[192]);
                gr.z = pk2(cp[256], cp[320]);
                gr.w = pk2(cp[384], cp[448]);
                CbL[g][n] = gr;
            }
            __syncthreads();
            #pragma unroll
            for (int ss = 0; ss < 4; ++ss) {          // 4 samples reuse the pack
                #pragma unroll
                for (int ks2 = 0; ks2 < 2; ++ks2) {
                    const float* ap = ab + (size_t)ss * DD + kc + ks2*32;
                    float4 xa = *((const float4*)ap);
                    float4 xc = *((const float4*)(ap + 4));
                    B8 a;
                    a.u[0] = pk2(xa.x, xa.y); a.u[1] = pk2(xa.z, xa.w);
                    a.u[2] = pk2(xc.x, xc.y); a.u[3] = pk2(xc.z, xc.w);
                    B8 b0, b1, b2, b3;
                    b0.q = CbL[ks2*4 + kq][(l & 15)];
                    b1.q = CbL[ks2*4 + kq][(l & 15) + 16];
                    b2.q = CbL[ks2*4 + kq][(l & 15) + 32];
                    b3.q = CbL[ks2*4 + kq][(l & 15) + 48];
                    acc[0] = __builtin_amdgcn_mfma_f32_16x16x32_bf16(a.v, b0.v, acc[0], 0, 0, 0);
                    acc[1] = __builtin_amdgcn_mfma_f32_16x16x32_bf16(a.v, b1.v, acc[1], 0, 0, 0);
                    acc[2] = __builtin_amdgcn_mfma_f32_16x16x32_bf16(a.v, b2.v, acc[2], 0, 0, 0);
                    acc[3] = __builtin_amdgcn_mfma_f32_16x16x32_bf16(a.v, b3.v, acc[3], 0, 0, 0);
                }
            }
        }
        int rw = r0 + w*16 + kq * 4;                  // D layout (m89)
        float* SPs = SP + (size_t)sp * 32768;         // 512x64 per partial
        #pragma unroll
        for (int ng = 0; ng < 4; ++ng) {
            int n = ng*16 + (l & 15);
            #pragma unroll
            for (int r = 0; r < 4; ++r)
                SPs[(size_t)(rw + r) * 64 + n] = acc[ng][r];
        }
    } else if (b < 328) {
        // T = X @ C via MFMA, self-packed C granules (verified R12 body)
        uint4 (*CbL)[64] = (uint4(*)[64])smem_raw;
        int r0 = (b - 200) * 64;
        int w  = tid >> 6, l = tid & 63;
        int rowA = r0 + w*16 + (l & 15);
        int kq   = l >> 4;
        const float* xb = X + (size_t)rowA * DD + kq * 8;
        f32x4 acc[4];
        #pragma unroll
        for (int ng = 0; ng < 4; ++ng) acc[ng] = (f32x4){0.f, 0.f, 0.f, 0.f};
        for (int kc = 0; kc < DD; kc += 64) {
            __syncthreads();
            #pragma unroll
            for (int u = 0; u < 2; ++u) {
                int g = (tid >> 6) + u*4;
                int n = tid & 63;
                const float* cp = C + (size_t)(kc + g*8) * 64 + n;
                uint4 gr;
                gr.x = pk2(cp[0],   cp[64]);
                gr.y = pk2(cp[128], cp[192]);
                gr.z = pk2(cp[256], cp[320]);
                gr.w = pk2(cp[384], cp[448]);
                CbL[g][n] = gr;
            }
            __syncthreads();
            #pragma unroll
            for (int ks2 = 0; ks2 < 2; ++ks2) {
                float4 xa = *((const float4*)(xb + kc + ks2*32));
                float4 xc = *((const float4*)(xb + kc + ks2*32 + 4));
                B8 a;
                a.u[0] = pk2(xa.x, xa.y); a.u[1] = pk2(xa.z, xa.w);
                a.u[2] = pk2(xc.x, xc.y); a.u[3] = pk2(xc.z, xc.w);
                B8 b0, b1, b2, b3;
                b0.q = CbL[ks2*4 + kq][(l & 15)];
                b1.q = CbL[ks2*4 + kq][(l & 15) + 16];
                b2.q = CbL[ks2*4 + kq][(l & 15) + 32];
                b3.q = CbL[ks2*4 + kq][(l & 15) + 48];
                acc[0] = __builtin_amdgcn_mfma_f32_16x16x32_bf16(a.v, b0.v, acc[0], 0, 0, 0);
                acc[1] = __builtin_amdgcn_mfma_f32_16x16x32_bf16(a.v, b1.v, acc[1], 0, 0, 0);
                acc[2] = __builtin_amdgcn_mfma_f32_16x16x32_bf16(a.v, b2.v, acc[2], 0, 0, 0);
                acc[3] = __builtin_amdgcn_mfma_f32_16x16x32_bf16(a.v, b3.v, acc[3], 0, 0, 0);
            }
        }
        int rw = r0 + w*16 + kq * 4;
        #pragma unroll
        for (int ng = 0; ng < 4; ++ng) {
            int n = ng*16 + (l & 15);
            #pragma unroll
            for (int r = 0; r < 4; ++r)
                Tb[(size_t)(rw + r) * 64 + n] = f2bf(acc[ng][r]);
        }
    } else if (b < 584) {
        // gram k-split partials (verified R11 body)
        int q  = b - 328;
        int j  = q & 63, ks = q >> 6;
        int i   = tid & 63;
        int seg = tid >> 6;
        int k0  = ks * 192 + seg * 48;
        float p = 0.f;
        for (int k = k0; k < k0 + 48; ++k)
            p += C[k * NC + i] * C[k * NC + j];
        float (*red)[64] = (float(*)[64])smem_raw;
        red[seg][i] = p;
        __syncthreads();
        if (seg == 0)
            gramP[(size_t)ks * 4096 + i * NC + j] =
                red[0][i] + red[1][i] + red[2][i] + red[3][i];
    } else {
        // U-partial = C^T[kslice] @ W[kslice][128 cols] (verified f32 body)
        int q  = b - 584;
        int nt = q >> 2, ks = q & 3;
        int n0 = nt * 128, kb = ks * 192;
        float (*Cu)[68]  = (float(*)[68])smem_raw;               // [32][68]
        float (*Wu)[132] = (float(*)[132])(smem_raw + 8704);     // [32][132]
        int tx = tid & 15, ty = tid >> 4;
        float4 a0[4], a1[4];
        #pragma unroll
        for (int i = 0; i < 4; ++i) { a0[i] = make_float4(0,0,0,0); a1[i] = make_float4(0,0,0,0); }
        for (int kc = kb; kc < kb + 192; kc += 32) {
            __syncthreads();
            {   int i4 = tid & 15, kk = tid >> 4;
                *((float4*)&Cu[kk][i4*4])    = *((const float4*)(C + (size_t)(kc+kk)*64 + i4*4));
                *((float4*)&Cu[kk+16][i4*4]) = *((const float4*)(C + (size_t)(kc+kk+16)*64 + i4*4));
            }
            {   int nf = tid & 31, kq2 = tid >> 5;
                #pragma unroll
                for (int u = 0; u < 4; ++u) {
                    int k = kq2 + u * 8;
                    int n = n0 + nf * 4;
                    float4 v = {0.f, 0.f, 0.f, 0.f};
                    if (n < NY) v = *((const float4*)(W + (size_t)(kc + k) * NY + n));
                    *((float4*)&Wu[k][nf*4]) = v;
                }
            }
            __syncthreads();
            #pragma unroll 8
            for (int k = 0; k < 32; ++k) {
                float4 ci = *((float4*)&Cu[k][ty*4]);
                float4 w0 = *((float4*)&Wu[k][tx*8]);
                float4 w1 = *((float4*)&Wu[k][tx*8+4]);
                FMA4(a0[0], ci.x, w0); FMA4(a1[0], ci.x, w1);
                FMA4(a0[1], ci.y, w0); FMA4(a1[1], ci.y, w1);
                FMA4(a0[2], ci.z, w0); FMA4(a1[2], ci.z, w1);
                FMA4(a0[3], ci.w, w0); FMA4(a1[3], ci.w, w1);
            }
        }
        float* Ups = Up + (size_t)ks * 64000;
        #pragma unroll
        for (int i = 0; i < 4; ++i) {
            int irow = ty * 4 + i;
            int n = n0 + tx * 8;
            if (n < NY)     *((float4*)(Ups + (size_t)irow * NY + n))     = a0[i];
            if (n + 4 < NY) *((float4*)(Ups + (size_t)irow * NY + n + 4)) = a1[i];
        }
    }
}

// ===== K2: inv (block 0) || S-reduce 25->1 + abs (blocks 1..8) — R13 verified =====
__global__ __launch_bounds__(256) void k_mid(
    const float* __restrict__ gramP, const float* __restrict__ SP,
    float* __restrict__ ginv, float* __restrict__ Sfin) {
    int blk = blockIdx.x, tid = threadIdx.x;
    if (blk == 0) {
        int c = tid & 63;
        int q = tid >> 6;
        float a[16], bb[16];
        #pragma unroll
        for (int i = 0; i < 16; ++i) {
            int r = q * 16 + i;
            size_t off = (size_t)r * 64 + c;
            a[i]  = gramP[off] + gramP[4096 + off] + gramP[8192 + off] + gramP[12288 + off];
            bb[i] = (r == c) ? 1.f : 0.f;
        }
        __shared__ float asr[2][64];
        __shared__ float bsr[2][64];
        for (int p = 0; p < 64; ++p) {
            int qp  = p >> 4;
            int lp  = p & 15;
            int par = p & 1;
            if (q == qp) {
                float ap = 0.f, bp = 0.f;
                #pragma unroll
                for (int i = 0; i < 16; ++i)
                    if (i == lp) { ap = a[i]; bp = bb[i]; }
                float App = __shfl(ap, p);
                float s   = 1.0f / App;
                asr[par][c] = ap * s;
                bsr[par][c] = bp * s;
            }
            __syncthreads();
            float as_ = asr[par][c];
            float bs_ = bsr[par][c];
            #pragma unroll
            for (int i = 0; i < 16; ++i) {
                float f = __shfl(a[i], p);
                bool isp = (q == qp) && (i == lp);
                a[i]  = isp ? as_ : fmaf(-f, as_, a[i]);
                bb[i] = isp ? bs_ : fmaf(-f, bs_, bb[i]);
            }
        }
        #pragma unroll
        for (int i = 0; i < 16; ++i)
            ginv[(q * 16 + i) * 64 + c] = bb[i];
    } else {
        // S-reduce: Sfin = |sum of 25 score partials| over rows 0..499
        int e = blk - 1;                              // 0..7, 4000 floats each
        for (int t = tid; t < 1000; t += 256) {
            size_t off = (size_t)e * 4000 + (size_t)t * 4;
            float4 s = {0.f, 0.f, 0.f, 0.f};
            #pragma unroll
            for (int p = 0; p < 25; ++p) {
                float4 v = *((const float4*)(SP + (size_t)p * 32768 + off));
                s.x += v.x; s.y += v.y; s.z += v.z; s.w += v.w;
            }
            float4 o = {fabsf(s.x), fabsf(s.y), fabsf(s.z), fabsf(s.w)};
            *((float4*)(Sfin + off)) = o;
        }
    }
}

// ===== K3: y = T @ (Ginv@Usum) + b, V computed IN-BLOCK (0..511) || sparse (512) =====
// R16 change: k_vc deleted. Each ypred block stages Ginv + its Usum slice,
// computes its 64x128 V-slice in f32 (~2K FMA/thread), packs bf16 granules in
// LDS, then runs the verified 128x128 MFMA. Removes one kernel + launch gap
// from the serial tail.
__global__ __launch_bounds__(256) void k_ypred(
    const uint4* __restrict__ Tbq, const float* __restrict__ ginv,
    const float* __restrict__ Up, const float* __restrict__ Sfin,
    const float* __restrict__ bh, float* __restrict__ Y,
    float* __restrict__ out2) {
    __shared__ __align__(16) char smem_raw[69632];
    int blk = blockIdx.x, tid = threadIdx.x;
    if (blk == 512) {
        // sparse losses from Sfin (verified body; colnorms cancel)
        __shared__ float colred[4][64];
        __shared__ float rn[64];
        __shared__ float trc[64];
        __shared__ float r1[4], r2[4];
        int c = tid & 63, seg = tid >> 6;
        float p = 0.f;
        for (int r = seg; r < NCL; r += 4) {
            float s = Sfin[r * 64 + c];
            p += s * s;
        }
        colred[seg][c] = p;
        __syncthreads();
        if (seg == 0) {
            float n2  = colred[0][c] + colred[1][c] + colred[2][c] + colred[3][c];
            float inv = 1.0f / fmaxf(sqrtf(n2), EPSN);
            rn[c]  = inv;
            trc[c] = n2 * inv * inv;
        }
        __syncthreads();
        float l1p = 0.f, l2p = 0.f;
        for (int r = tid; r < NCL; r += 256) {
            float rs = 0.f;
            #pragma unroll
            for (int cc = 0; cc < 64; ++cc)
                rs += Sfin[r * 64 + cc] * rn[cc];
            l1p += rs;
            l2p += rs * rs;
        }
        #pragma unroll
        for (int off = 32; off > 0; off >>= 1) {
            l1p += __shfl_down(l1p, off);
            l2p += __shfl_down(l2p, off);
        }
        int wave = tid >> 6, lane = tid & 63;
        if (lane == 0) { r1[wave] = l1p; r2[wave] = l2p; }
        __syncthreads();
        if (tid == 0) {
            float L1 = r1[0] + r1[1] + r1[2] + r1[3];
            float L2 = r2[0] + r2[1] + r2[2] + r2[3];
            float tr = 0.f;
            #pragma unroll
            for (int cc = 0; cc < 64; ++cc) tr += trc[cc];
            out2[0] = L1;
            out2[1] = L2 - tr;
        }
        return;
    }
    float (*Gs)[68]  = (float(*)[68])smem_raw;                       // 17408 B
    float (*Us)[132] = (float(*)[132])(smem_raw + 17408);            // 33792 B
    unsigned short* VbL = (unsigned short*)(smem_raw + 17408 + 33792); // [128][72] hw, 18432 B
    int rb = blk >> 3, cb = blk & 7;
    int r0g = rb * 128, c0g = cb * 128;
    {   // stage Ginv [64][64]
        #pragma unroll
        for (int p = 0; p < 4; ++p) {
            int f = tid + p * 256;
            int j = f >> 4, n4 = f & 15;
            *((float4*)&Gs[j][n4*4]) = *((const float4*)(ginv + (size_t)j * 64 + n4*4));
        }
    }
    {   // stage Usum slice [64][128] (sum 4 partials; zero-pad n >= 1000)
        const float* Up0 = Up;
        const float* Up1 = Up + 64000;
        const float* Up2 = Up + 128000;
        const float* Up3 = Up + 192000;
        #pragma unroll
        for (int p = 0; p < 8; ++p) {
            int f = tid + p * 256;
            int j = f >> 5, n8 = f & 31;
            int n = c0g + n8 * 4;
            float4 v = {0.f, 0.f, 0.f, 0.f};
            if (n < NY) {
                float4 u0 = *((const float4*)(Up0 + (size_t)j * NY + n));
                float4 u1 = *((const float4*)(Up1 + (size_t)j * NY + n));
                float4 u2 = *((const float4*)(Up2 + (size_t)j * NY + n));
                float4 u3 = *((const float4*)(Up3 + (size_t)j * NY + n));
                v.x = u0.x + u1.x + u2.x + u3.x;
                v.y = u0.y + u1.y + u2.y + u3.y;
                v.z = u0.z + u1.z + u2.z + u3.z;
                v.w = u0.w + u1.w + u2.w + u3.w;
            }
            *((float4*)&Us[j][n8*4]) = v;
        }
    }
    __syncthreads();
    // V slice: thread (tx=tid&31 -> cols tx*4..+3, ty=tid>>5) computes
    // k rows {rh*32 + ty*4 .. +3}. V[k][n] = sum_j Gs[j][k] (symmetric) * Us[j][n].
    int tx = tid & 31, ty = tid >> 5;
    float4 vr[2][4];
    #pragma unroll
    for (int rh = 0; rh < 2; ++rh)
        #pragma unroll
        for (int i = 0; i < 4; ++i) vr[rh][i] = make_float4(0.f, 0.f, 0.f, 0.f);
    #pragma unroll
    for (int rh = 0; rh < 2; ++rh) {
        int k0 = rh * 32 + ty * 4;
        #pragma unroll 4
        for (int j = 0; j < 64; ++j) {
            float4 g = *((float4*)&Gs[j][k0]);      // broadcast-ish (2 addrs/wave)
            float4 u = *((float4*)&Us[j][tx*4]);
            FMA4(vr[rh][0], g.x, u);
            FMA4(vr[rh][1], g.y, u);
            FMA4(vr[rh][2], g.z, u);
            FMA4(vr[rh][3], g.w, u);
        }
    }
    // pack bf16 granules: VbL[n][g*8 + (k&7)], row stride 72 halfwords (144 B)
    #pragma unroll
    for (int rh = 0; rh < 2; ++rh) {
        #pragma unroll
        for (int i = 0; i < 4; ++i) {
            int k = rh * 32 + ty * 4 + i;
            int base = (k >> 3) * 8 + (k & 7);
            VbL[(tx*4 + 0) * 72 + base] = f2bf(vr[rh][i].x);
            VbL[(tx*4 + 1) * 72 + base] = f2bf(vr[rh][i].y);
            VbL[(tx*4 + 2) * 72 + base] = f2bf(vr[rh][i].z);
            VbL[(tx*4 + 3) * 72 + base] = f2bf(vr[rh][i].w);
        }
    }
    __syncthreads();
    // MFMA 128x128 (verified R13 structure), B-frags from VbL
    int w = tid >> 6, l = tid & 63;
    int wr = (w >> 1) * 64, wc = (w & 1) * 64;
    int kq = l >> 4, ln = l & 15;
    f32x4 acc[4][4];
    #pragma unroll
    for (int rg = 0; rg < 4; ++rg)
        #pragma unroll
        for (int ng = 0; ng < 4; ++ng) acc[rg][ng] = (f32x4){0.f,0.f,0.f,0.f};
    #pragma unroll
    for (int ks = 0; ks < 2; ++ks) {
        B8 a[4], bb[4];
        #pragma unroll
        for (int rg = 0; rg < 4; ++rg) {
            int row = r0g + wr + rg*16 + ln;
            a[rg].q = Tbq[(size_t)row * 8 + ks*4 + kq];
        }
        #pragma unroll
        for (int ng = 0; ng < 4; ++ng) {
            int nl = wc + ng*16 + ln;                 // 0..127 local col
            bb[ng].q = *((const uint4*)(VbL + nl*72 + (ks*4 + kq)*8));
        }
        #pragma unroll
        for (int rg = 0; rg < 4; ++rg)
            #pragma unroll
            for (int ng = 0; ng < 4; ++ng)
                acc[rg][ng] = __builtin_amdgcn_mfma_f32_16x16x32_bf16(
                    a[rg].v, bb[ng].v, acc[rg][ng], 0, 0, 0);
    }
    #pragma unroll
    for (int ng = 0; ng < 4; ++ng) {
        int n = c0g + wc + ng*16 + ln;
        if (n < NY) {
            float bias = bh[n];
            #pragma unroll
            for (int rg = 0; rg < 4; ++rg) {
                int row = r0g + wr + rg*16 + kq*4;
                #pragma unroll
                for (int r = 0; r < 4; ++r)
                    Y[(size_t)(row + r) * NY + n] = acc[rg][ng][r] + bias;
            }
        }
    }
}

extern "C" void kernel_launch(void* const* d_in, const int* in_sizes, int n_in,
                              void* d_out, int out_size, void* d_ws, size_t ws_size,
                              hipStream_t stream) {
    const float* X        = (const float*)d_in[0];   // [8192,768]
    const float* clusters = (const float*)d_in[1];   // [500,100,768]
    const float* C        = (const float*)d_in[2];   // [768,64]
    const float* W        = (const float*)d_in[3];   // [768,1000]
    const float* bh       = (const float*)d_in[4];   // [1000]
    float* out = (float*)d_out;                      // y_pred, L1, L2
    float* ws  = (float*)d_ws;

    float* gramP = ws;                    // 4 x 4096 = 16384
    float* ginv  = gramP + 16384;         // 4096
    float* Up    = ginv  + 4096;          // 4 x 64000 = 256000
    float* SP    = Up    + 256000;        // 25 x 32768 = 819200 (score partials)
    float* Sfin  = SP    + 819200;        // 32768 (500x64 used)
    float* TbF   = Sfin  + 32768;         // 262144 floats (Tb bf16, 1 MB)

    unsigned short* Tb = (unsigned short*)TbF;

    k_front <<<dim3(616), dim3(256), 0, stream>>>(clusters, C, W, X, gramP, Up, SP, Tb);
    k_mid   <<<dim3(9),   dim3(256), 0, stream>>>(gramP, SP, ginv, Sfin);
    k_ypred <<<dim3(513), dim3(256), 0, stream>>>((const uint4*)Tb, ginv, Up, Sfin,
                                                  bh, out, out + (size_t)BS * NY);
}

// Round 18
// 146.748 us; speedup vs baseline: 1.0621x; 1.0167x over previous
//
#include <hip/hip_runtime.h>
#include <hip/hip_bf16.h>
#include <math.h>

#define BS   8192
#define DD   768
#define NC   64
#define NCL  500
#define CS   100
#define NY   1000
#define EPSN 1e-12f

typedef __attribute__((ext_vector_type(8))) short bf16x8;
typedef __attribute__((ext_vector_type(4))) float f32x4;

union B8 { unsigned u[4]; bf16x8 v; uint4 q; };

__device__ inline unsigned short f2bf(float x) {
    __hip_bfloat16 h = __float2bfloat16(x);
    return *reinterpret_cast<unsigned short*>(&h);
}
__device__ inline unsigned pk2(float a, float b) {
    return (unsigned)f2bf(a) | ((unsigned)f2bf(b) << 16);
}

#define FMA4(acc, s, v) { (acc).x = fmaf((s), (v).x, (acc).x); \
                          (acc).y = fmaf((s), (v).y, (acc).y); \
                          (acc).z = fmaf((s), (v).z, (acc).z); \
                          (acc).w = fmaf((s), (v).w, (acc).w); }

// ===== K1: score MFMA (200) || tmat MFMA (128) || gram ksplit (256) || U (32) =====
// Best-measured config (R14: 146.6us). clusters-scan wall: ~87us / 2.1 TB/s
// effective across 5 implementation variants — unexplained by available counters.
__global__ __launch_bounds__(256) void k_front(
    const float* __restrict__ clusters, const float* __restrict__ C,
    const float* __restrict__ W, const float* __restrict__ X,
    float* __restrict__ gramP, float* __restrict__ Up,
    float* __restrict__ SP, unsigned short* __restrict__ Tb) {
    __shared__ __align__(16) char smem_raw[25600];
    int b = blockIdx.x, tid = threadIdx.x;
    if (b < 200) {
        // score partial: rows rt*64..+63, samples sp*4..+3 (K-eff = 4*768)
        int rt = b / 25, sp = b % 25;
        uint4 (*CbL)[64] = (uint4(*)[64])smem_raw;    // [8][64] C granules, 8 KB
        int r0 = rt * 64;
        int w  = tid >> 6, l = tid & 63;
        int rowA = r0 + w*16 + (l & 15);
        int rcl  = rowA < NCL ? rowA : (NCL - 1);     // clamp; rows >=500 unread
        int kq   = l >> 4;
        const float* ab = clusters + (size_t)rcl * CS * DD + (size_t)sp * 4 * DD + kq * 8;
        f32x4 acc[4];
        #pragma unroll
        for (int ng = 0; ng < 4; ++ng) acc[ng] = (f32x4){0.f, 0.f, 0.f, 0.f};
        for (int kc = 0; kc < DD; kc += 64) {
            __syncthreads();
            #pragma unroll
            for (int u = 0; u < 2; ++u) {             // pack C[kc..kc+64) granules
                int g = (tid >> 6) + u*4;
                int n = tid & 63;
                const float* cp = C + (size_t)(kc + g*8) * 64 + n;
                uint4 gr;
                gr.x = pk2(cp[0],   cp[64]);
                gr.y = pk2(cp[128], cp[192]);
                gr.z = pk2(cp[256], cp[320]);
                gr.w = pk2(cp[384], cp[448]);
                CbL[g][n] = gr;
            }
            __syncthreads();
            #pragma unroll
            for (int ss = 0; ss < 4; ++ss) {          // 4 samples reuse the pack
                #pragma unroll
                for (int ks2 = 0; ks2 < 2; ++ks2) {
                    const float* ap = ab + (size_t)ss * DD + kc + ks2*32;
                    float4 xa = *((const float4*)ap);
                    float4 xc = *((const float4*)(ap + 4));
                    B8 a;
                    a.u[0] = pk2(xa.x, xa.y); a.u[1] = pk2(xa.z, xa.w);
                    a.u[2] = pk2(xc.x, xc.y); a.u[3] = pk2(xc.z, xc.w);
                    B8 b0, b1, b2, b3;
                    b0.q = CbL[ks2*4 + kq][(l & 15)];
                    b1.q = CbL[ks2*4 + kq][(l & 15) + 16];
                    b2.q = CbL[ks2*4 + kq][(l & 15) + 32];
                    b3.q = CbL[ks2*4 + kq][(l & 15) + 48];
                    acc[0] = __builtin_amdgcn_mfma_f32_16x16x32_bf16(a.v, b0.v, acc[0], 0, 0, 0);
                    acc[1] = __builtin_amdgcn_mfma_f32_16x16x32_bf16(a.v, b1.v, acc[1], 0, 0, 0);
                    acc[2] = __builtin_amdgcn_mfma_f32_16x16x32_bf16(a.v, b2.v, acc[2], 0, 0, 0);
                    acc[3] = __builtin_amdgcn_mfma_f32_16x16x32_bf16(a.v, b3.v, acc[3], 0, 0, 0);
                }
            }
        }
        int rw = r0 + w*16 + kq * 4;                  // D layout (m89)
        float* SPs = SP + (size_t)sp * 32768;         // 512x64 per partial
        #pragma unroll
        for (int ng = 0; ng < 4; ++ng) {
            int n = ng*16 + (l & 15);
            #pragma unroll
            for (int r = 0; r < 4; ++r)
                SPs[(size_t)(rw + r) * 64 + n] = acc[ng][r];
        }
    } else if (b < 328) {
        // T = X @ C via MFMA, self-packed C granules (verified R12 body)
        uint4 (*CbL)[64] = (uint4(*)[64])smem_raw;
        int r0 = (b - 200) * 64;
        int w  = tid >> 6, l = tid & 63;
        int rowA = r0 + w*16 + (l & 15);
        int kq   = l >> 4;
        const float* xb = X + (size_t)rowA * DD + kq * 8;
        f32x4 acc[4];
        #pragma unroll
        for (int ng = 0; ng < 4; ++ng) acc[ng] = (f32x4){0.f, 0.f, 0.f, 0.f};
        for (int kc = 0; kc < DD; kc += 64) {
            __syncthreads();
            #pragma unroll
            for (int u = 0; u < 2; ++u) {
                int g = (tid >> 6) + u*4;
                int n = tid & 63;
                const float* cp = C + (size_t)(kc + g*8) * 64 + n;
                uint4 gr;
                gr.x = pk2(cp[0],   cp[64]);
                gr.y = pk2(cp[128], cp[192]);
                gr.z = pk2(cp[256], cp[320]);
                gr.w = pk2(cp[384], cp[448]);
                CbL[g][n] = gr;
            }
            __syncthreads();
            #pragma unroll
            for (int ks2 = 0; ks2 < 2; ++ks2) {
                float4 xa = *((const float4*)(xb + kc + ks2*32));
                float4 xc = *((const float4*)(xb + kc + ks2*32 + 4));
                B8 a;
                a.u[0] = pk2(xa.x, xa.y); a.u[1] = pk2(xa.z, xa.w);
                a.u[2] = pk2(xc.x, xc.y); a.u[3] = pk2(xc.z, xc.w);
                B8 b0, b1, b2, b3;
                b0.q = CbL[ks2*4 + kq][(l & 15)];
                b1.q = CbL[ks2*4 + kq][(l & 15) + 16];
                b2.q = CbL[ks2*4 + kq][(l & 15) + 32];
                b3.q = CbL[ks2*4 + kq][(l & 15) + 48];
                acc[0] = __builtin_amdgcn_mfma_f32_16x16x32_bf16(a.v, b0.v, acc[0], 0, 0, 0);
                acc[1] = __builtin_amdgcn_mfma_f32_16x16x32_bf16(a.v, b1.v, acc[1], 0, 0, 0);
                acc[2] = __builtin_amdgcn_mfma_f32_16x16x32_bf16(a.v, b2.v, acc[2], 0, 0, 0);
                acc[3] = __builtin_amdgcn_mfma_f32_16x16x32_bf16(a.v, b3.v, acc[3], 0, 0, 0);
            }
        }
        int rw = r0 + w*16 + kq * 4;
        #pragma unroll
        for (int ng = 0; ng < 4; ++ng) {
            int n = ng*16 + (l & 15);
            #pragma unroll
            for (int r = 0; r < 4; ++r)
                Tb[(size_t)(rw + r) * 64 + n] = f2bf(acc[ng][r]);
        }
    } else if (b < 584) {
        // gram k-split partials (verified R11 body)
        int q  = b - 328;
        int j  = q & 63, ks = q >> 6;
        int i   = tid & 63;
        int seg = tid >> 6;
        int k0  = ks * 192 + seg * 48;
        float p = 0.f;
        for (int k = k0; k < k0 + 48; ++k)
            p += C[k * NC + i] * C[k * NC + j];
        float (*red)[64] = (float(*)[64])smem_raw;
        red[seg][i] = p;
        __syncthreads();
        if (seg == 0)
            gramP[(size_t)ks * 4096 + i * NC + j] =
                red[0][i] + red[1][i] + red[2][i] + red[3][i];
    } else {
        // U-partial = C^T[kslice] @ W[kslice][128 cols] (verified f32 body)
        int q  = b - 584;
        int nt = q >> 2, ks = q & 3;
        int n0 = nt * 128, kb = ks * 192;
        float (*Cu)[68]  = (float(*)[68])smem_raw;               // [32][68]
        float (*Wu)[132] = (float(*)[132])(smem_raw + 8704);     // [32][132]
        int tx = tid & 15, ty = tid >> 4;
        float4 a0[4], a1[4];
        #pragma unroll
        for (int i = 0; i < 4; ++i) { a0[i] = make_float4(0,0,0,0); a1[i] = make_float4(0,0,0,0); }
        for (int kc = kb; kc < kb + 192; kc += 32) {
            __syncthreads();
            {   int i4 = tid & 15, kk = tid >> 4;
                *((float4*)&Cu[kk][i4*4])    = *((const float4*)(C + (size_t)(kc+kk)*64 + i4*4));
                *((float4*)&Cu[kk+16][i4*4]) = *((const float4*)(C + (size_t)(kc+kk+16)*64 + i4*4));
            }
            {   int nf = tid & 31, kq2 = tid >> 5;
                #pragma unroll
                for (int u = 0; u < 4; ++u) {
                    int k = kq2 + u * 8;
                    int n = n0 + nf * 4;
                    float4 v = {0.f, 0.f, 0.f, 0.f};
                    if (n < NY) v = *((const float4*)(W + (size_t)(kc + k) * NY + n));
                    *((float4*)&Wu[k][nf*4]) = v;
                }
            }
            __syncthreads();
            #pragma unroll 8
            for (int k = 0; k < 32; ++k) {
                float4 ci = *((float4*)&Cu[k][ty*4]);
                float4 w0 = *((float4*)&Wu[k][tx*8]);
                float4 w1 = *((float4*)&Wu[k][tx*8+4]);
                FMA4(a0[0], ci.x, w0); FMA4(a1[0], ci.x, w1);
                FMA4(a0[1], ci.y, w0); FMA4(a1[1], ci.y, w1);
                FMA4(a0[2], ci.z, w0); FMA4(a1[2], ci.z, w1);
                FMA4(a0[3], ci.w, w0); FMA4(a1[3], ci.w, w1);
            }
        }
        float* Ups = Up + (size_t)ks * 64000;
        #pragma unroll
        for (int i = 0; i < 4; ++i) {
            int irow = ty * 4 + i;
            int n = n0 + tx * 8;
            if (n < NY)     *((float4*)(Ups + (size_t)irow * NY + n))     = a0[i];
            if (n + 4 < NY) *((float4*)(Ups + (size_t)irow * NY + n + 4)) = a1[i];
        }
    }
}

// ===== K2: inv (block 0) || S-reduce 25->1 + abs (blocks 1..8) — verified =====
__global__ __launch_bounds__(256) void k_mid(
    const float* __restrict__ gramP, const float* __restrict__ SP,
    float* __restrict__ ginv, float* __restrict__ Sfin) {
    int blk = blockIdx.x, tid = threadIdx.x;
    if (blk == 0) {
        int c = tid & 63;
        int q = tid >> 6;
        float a[16], bb[16];
        #pragma unroll
        for (int i = 0; i < 16; ++i) {
            int r = q * 16 + i;
            size_t off = (size_t)r * 64 + c;
            a[i]  = gramP[off] + gramP[4096 + off] + gramP[8192 + off] + gramP[12288 + off];
            bb[i] = (r == c) ? 1.f : 0.f;
        }
        __shared__ float asr[2][64];
        __shared__ float bsr[2][64];
        for (int p = 0; p < 64; ++p) {
            int qp  = p >> 4;
            int lp  = p & 15;
            int par = p & 1;
            if (q == qp) {
                float ap = 0.f, bp = 0.f;
                #pragma unroll
                for (int i = 0; i < 16; ++i)
                    if (i == lp) { ap = a[i]; bp = bb[i]; }
                float App = __shfl(ap, p);
                float s   = 1.0f / App;
                asr[par][c] = ap * s;
                bsr[par][c] = bp * s;
            }
            __syncthreads();
            float as_ = asr[par][c];
            float bs_ = bsr[par][c];
            #pragma unroll
            for (int i = 0; i < 16; ++i) {
                float f = __shfl(a[i], p);
                bool isp = (q == qp) && (i == lp);
                a[i]  = isp ? as_ : fmaf(-f, as_, a[i]);
                bb[i] = isp ? bs_ : fmaf(-f, bs_, bb[i]);
            }
        }
        #pragma unroll
        for (int i = 0; i < 16; ++i)
            ginv[(q * 16 + i) * 64 + c] = bb[i];
    } else {
        // S-reduce: Sfin = |sum of 25 score partials| over rows 0..499
        int e = blk - 1;                              // 0..7, 4000 floats each
        for (int t = tid; t < 1000; t += 256) {
            size_t off = (size_t)e * 4000 + (size_t)t * 4;
            float4 s = {0.f, 0.f, 0.f, 0.f};
            #pragma unroll
            for (int p = 0; p < 25; ++p) {
                float4 v = *((const float4*)(SP + (size_t)p * 32768 + off));
                s.x += v.x; s.y += v.y; s.z += v.z; s.w += v.w;
            }
            float4 o = {fabsf(s.x), fabsf(s.y), fabsf(s.z), fabsf(s.w)};
            *((float4*)(Sfin + off)) = o;
        }
    }
}

// ====== K3: Vb = bf16[(Ginv @ sum Up)^T] granules (0..15) || sparse (16) ======
__global__ __launch_bounds__(256) void k_vc(
    const float* __restrict__ ginv, const float* __restrict__ Up,
    const float* __restrict__ Sfin, unsigned short* __restrict__ Vb,
    float* __restrict__ out2) {
    __shared__ __align__(16) char smem_raw[34816];
    int blk = blockIdx.x, tid = threadIdx.x;
    if (blk == 16) {
        // sparse losses from Sfin (verified logic; colnorms cancel)
        __shared__ float colred[4][64];
        __shared__ float rn[64];
        __shared__ float trc[64];
        __shared__ float r1[4], r2[4];
        int c = tid & 63, seg = tid >> 6;
        float p = 0.f;
        for (int r = seg; r < NCL; r += 4) {
            float s = Sfin[r * 64 + c];
            p += s * s;
        }
        colred[seg][c] = p;
        __syncthreads();
        if (seg == 0) {
            float n2  = colred[0][c] + colred[1][c] + colred[2][c] + colred[3][c];
            float inv = 1.0f / fmaxf(sqrtf(n2), EPSN);
            rn[c]  = inv;
            trc[c] = n2 * inv * inv;
        }
        __syncthreads();
        float l1p = 0.f, l2p = 0.f;
        for (int r = tid; r < NCL; r += 256) {
            float rs = 0.f;
            #pragma unroll
            for (int cc = 0; cc < 64; ++cc)
                rs += Sfin[r * 64 + cc] * rn[cc];
            l1p += rs;
            l2p += rs * rs;
        }
        #pragma unroll
        for (int off = 32; off > 0; off >>= 1) {
            l1p += __shfl_down(l1p, off);
            l2p += __shfl_down(l2p, off);
        }
        int wave = tid >> 6, lane = tid & 63;
        if (lane == 0) { r1[wave] = l1p; r2[wave] = l2p; }
        __syncthreads();
        if (tid == 0) {
            float L1 = r1[0] + r1[1] + r1[2] + r1[3];
            float L2 = r2[0] + r2[1] + r2[2] + r2[3];
            float tr = 0.f;
            #pragma unroll
            for (int cc = 0; cc < 64; ++cc) tr += trc[cc];
            out2[0] = L1;
            out2[1] = L2 - tr;
        }
        return;
    }
    // V = Ginv @ Usum (f32), emitted transposed bf16 (B-fragment layout)
    float (*Us)[68] = (float(*)[68])smem_raw;                     // [64][68]
    float (*Gs)[68] = (float(*)[68])(smem_raw + 64*68*4);         // [64][68]
    int c0 = blk * 64;
    int tx = tid & 15, ty = tid >> 4;
    const float* Up0 = Up;
    const float* Up1 = Up + 64000;
    const float* Up2 = Up + 128000;
    const float* Up3 = Up + 192000;
    #pragma unroll
    for (int p = 0; p < 4; ++p) {
        int f = tid + p * 256;
        int j = f >> 4, n4 = f & 15;
        int n = c0 + n4 * 4;
        float4 v = {0.f, 0.f, 0.f, 0.f};
        if (n < NY) {
            float4 u0 = *((const float4*)(Up0 + (size_t)j * NY + n));
            float4 u1 = *((const float4*)(Up1 + (size_t)j * NY + n));
            float4 u2 = *((const float4*)(Up2 + (size_t)j * NY + n));
            float4 u3 = *((const float4*)(Up3 + (size_t)j * NY + n));
            v.x = u0.x + u1.x + u2.x + u3.x;
            v.y = u0.y + u1.y + u2.y + u3.y;
            v.z = u0.z + u1.z + u2.z + u3.z;
            v.w = u0.w + u1.w + u2.w + u3.w;
        }
        *((float4*)&Us[j][n4*4]) = v;
        *((float4*)&Gs[j][n4*4]) = *((const float4*)(ginv + (size_t)j * 64 + n4*4));
    }
    __syncthreads();
    float4 acc[4];
    #pragma unroll
    for (int i = 0; i < 4; ++i) acc[i] = make_float4(0.f,0.f,0.f,0.f);
    for (int j0 = 0; j0 < 64; j0 += 4) {
        #pragma unroll
        for (int jj = 0; jj < 4; ++jj) {
            float4 g = *((float4*)&Gs[j0+jj][ty*4]);   // Ginv symmetric
            float4 u = *((float4*)&Us[j0+jj][tx*4]);
            FMA4(acc[0], g.x, u);
            FMA4(acc[1], g.y, u);
            FMA4(acc[2], g.z, u);
            FMA4(acc[3], g.w, u);
        }
    }
    #pragma unroll
    for (int i = 0; i < 4; ++i) {
        int krow = ty * 4 + i;
        Vb[(size_t)(c0 + tx*4 + 0) * 64 + krow] = f2bf(acc[i].x);
        Vb[(size_t)(c0 + tx*4 + 1) * 64 + krow] = f2bf(acc[i].y);
        Vb[(size_t)(c0 + tx*4 + 2) * 64 + krow] = f2bf(acc[i].z);
        Vb[(size_t)(c0 + tx*4 + 3) * 64 + krow] = f2bf(acc[i].w);
    }
}

// ============ K4: y = T @ V + b via MFMA, 128x128, zero LDS — verified ============
__global__ __launch_bounds__(256) void k_ypred(
    const uint4* __restrict__ Tbq, const uint4* __restrict__ Vbq,
    const float* __restrict__ bh, float* __restrict__ Y) {
    int blk = blockIdx.x, tid = threadIdx.x;
    int rb = blk >> 3, cb = blk & 7;
    int r0g = rb * 128, c0g = cb * 128;
    int w = tid >> 6, l = tid & 63;
    int wr = (w >> 1) * 64, wc = (w & 1) * 64;
    int kq = l >> 4, ln = l & 15;
    f32x4 acc[4][4];
    #pragma unroll
    for (int rg = 0; rg < 4; ++rg)
        #pragma unroll
        for (int ng = 0; ng < 4; ++ng) acc[rg][ng] = (f32x4){0.f,0.f,0.f,0.f};
    #pragma unroll
    for (int ks = 0; ks < 2; ++ks) {
        B8 a[4], bb[4];
        #pragma unroll
        for (int rg = 0; rg < 4; ++rg) {
            int row = r0g + wr + rg*16 + ln;
            a[rg].q = Tbq[(size_t)row * 8 + ks*4 + kq];
        }
        #pragma unroll
        for (int ng = 0; ng < 4; ++ng) {
            int n = c0g + wc + ng*16 + ln;
            bb[ng].q = Vbq[(size_t)n * 8 + ks*4 + kq];
        }
        #pragma unroll
        for (int rg = 0; rg < 4; ++rg)
            #pragma unroll
            for (int ng = 0; ng < 4; ++ng)
                acc[rg][ng] = __builtin_amdgcn_mfma_f32_16x16x32_bf16(
                    a[rg].v, bb[ng].v, acc[rg][ng], 0, 0, 0);
    }
    #pragma unroll
    for (int ng = 0; ng < 4; ++ng) {
        int n = c0g + wc + ng*16 + ln;
        if (n < NY) {
            float bias = bh[n];
            #pragma unroll
            for (int rg = 0; rg < 4; ++rg) {
                int row = r0g + wr + rg*16 + kq*4;
                #pragma unroll
                for (int r = 0; r < 4; ++r)
                    Y[(size_t)(row + r) * NY + n] = acc[rg][ng][r] + bias;
            }
        }
    }
}

extern "C" void kernel_launch(void* const* d_in, const int* in_sizes, int n_in,
                              void* d_out, int out_size, void* d_ws, size_t ws_size,
                              hipStream_t stream) {
    const float* X        = (const float*)d_in[0];   // [8192,768]
    const float* clusters = (const float*)d_in[1];   // [500,100,768]
    const float* C        = (const float*)d_in[2];   // [768,64]
    const float* W        = (const float*)d_in[3];   // [768,1000]
    const float* bh       = (const float*)d_in[4];   // [1000]
    float* out = (float*)d_out;                      // y_pred, L1, L2
    float* ws  = (float*)d_ws;

    float* gramP = ws;                    // 4 x 4096 = 16384
    float* ginv  = gramP + 16384;         // 4096
    float* Up    = ginv  + 4096;          // 4 x 64000 = 256000
    float* SP    = Up    + 256000;        // 25 x 32768 = 819200 (score partials)
    float* Sfin  = SP    + 819200;        // 32768 (500x64 used)
    float* TbF   = Sfin  + 32768;         // 262144 floats (Tb bf16, 1 MB)
    float* VbF   = TbF   + 262144;        // 32768 floats (Vb bf16, 128 KB)

    unsigned short* Tb = (unsigned short*)TbF;
    unsigned short* Vb = (unsigned short*)VbF;

    k_front <<<dim3(616), dim3(256), 0, stream>>>(clusters, C, W, X, gramP, Up, SP, Tb);
    k_mid   <<<dim3(9),   dim3(256), 0, stream>>>(gramP, SP, ginv, Sfin);
    k_vc    <<<dim3(17),  dim3(256), 0, stream>>>(ginv, Up, Sfin, Vb, out + (size_t)BS * NY);
    k_ypred <<<dim3(512), dim3(256), 0, stream>>>((const uint4*)Tb, (const uint4*)Vb, bh, out);
}